// Round 2
// baseline (226.219 us; speedup 1.0000x reference)
//
#include <hip/hip_runtime.h>
#include <math.h>

#define B_TOT 2048
#define L_IN  70
#define D_INC 15
#define HID   16
#define NFC   4
#define KW    40
#define CCH   20
#define LP    31
#define SIGCH 8420
#define NOUT  128
#define KSPLIT 16
#define KLEN   528   // 16*528 = 8448 >= 8420

// ---------------------------------------------------------------------------
// Kernel 1: augment. block = 128 threads = 16 hid x 2 pos-half x 4 batch.
// grid = 512 (4 batches per block). LDS ~57 KB -> 2 blocks/CU.
// ---------------------------------------------------------------------------
__global__ __launch_bounds__(128) void k_augment(
    const float* __restrict__ x,  const float* __restrict__ w1, const float* __restrict__ b1,
    const float* __restrict__ w2, const float* __restrict__ b2,
    const float* __restrict__ w3, const float* __restrict__ b3,
    float* __restrict__ path)
{
    __shared__ float xs[4 * 1068];          // padded stride (needs >= 1065)
    __shared__ float w1s[9600];             // [m][h], m = c*40+k ; aliased by h1s later
    __shared__ float wsmall[356];           // w2(256) b2(16) w3(64) b3(4) b1(16)
    float* w2s = wsmall;        float* b2s = wsmall + 256;
    float* w3s = wsmall + 272;  float* b3s = wsmall + 336;
    float* b1s = wsmall + 340;
    float* h1s = w1s;                       // alias: 124*17 = 2108 floats (after barrier)

    const int tid = threadIdx.x;
    const int b0  = blockIdx.x * 4;

    for (int i = tid; i < 4 * 1050; i += 128) {
        int bl = i / 1050; int t = i - bl * 1050;
        xs[bl * 1068 + t] = x[(size_t)b0 * 1050 + i];   // contiguous read
    }
    for (int i = tid; i < 9600; i += 128) {
        int h = i / 600; int m = i - h * 600;           // m = c*40+k
        w1s[m * 16 + h] = w1[i];
    }
    for (int i = tid; i < 256; i += 128) w2s[i] = w2[i];   // FIX: block has 128 thr
    if (tid < 16)  b2s[tid] = b2[tid];
    if (tid < 64)  w3s[tid] = w3[tid];
    if (tid < 4)   b3s[tid] = b3[tid];
    if (tid < 16)  b1s[tid] = b1[tid];
    __syncthreads();

    const int h     = tid & 15;
    const int ph    = (tid >> 4) & 1;
    const int bl    = tid >> 5;
    const int pbase = ph * 16;

    float acc[16];
#pragma unroll
    for (int p = 0; p < 16; ++p) acc[p] = 0.f;

    for (int c = 0; c < D_INC; ++c) {
        float xcol[55];
        const int base = bl * 1068 + pbase * 15 + c;
#pragma unroll
        for (int i = 0; i < 55; ++i) xcol[i] = xs[base + i * 15];
#pragma unroll
        for (int k = 0; k < KW; ++k) {
            const float wv = w1s[(c * 40 + k) * 16 + h];
#pragma unroll
            for (int p = 0; p < 16; ++p) acc[p] += xcol[p + k] * wv;
        }
    }
    __syncthreads();            // all w1s reads done before alias write
    const float bb1 = b1s[h];
#pragma unroll
    for (int p = 0; p < 16; ++p) {
        int pos = pbase + p;
        if (pos < LP) h1s[(bl * 31 + pos) * 17 + h] = fmaxf(acc[p] + bb1, 0.f);
    }
    __syncthreads();

    if (tid < 124) {            // 4 batches * 31 positions
        const int bl2 = tid / 31;
        const int pos = tid - bl2 * 31;
        float hr[16];
#pragma unroll
        for (int c2 = 0; c2 < 16; ++c2) hr[c2] = h1s[tid * 17 + c2];
        float h2[16];
#pragma unroll
        for (int o = 0; o < 16; ++o) {
            float s = b2s[o];
#pragma unroll
            for (int c2 = 0; c2 < 16; ++c2) s += w2s[o * 16 + c2] * hr[c2];
            h2[o] = fmaxf(s, 0.f);
        }
        float h3[4];
#pragma unroll
        for (int f = 0; f < 4; ++f) {
            float s = b3s[f];
#pragma unroll
            for (int c2 = 0; c2 < 16; ++c2) s += w3s[f * 16 + c2] * h2[c2];
            h3[f] = s;
        }
        float* pr = path + ((size_t)(b0 + bl2) * LP + pos) * CCH;
#pragma unroll
        for (int d = 0; d < D_INC; ++d) pr[d] = xs[bl2 * 1068 + (pos + 39) * 15 + d];
        pr[15] = (float)pos * (1.0f / 30.0f);
#pragma unroll
        for (int f = 0; f < 4; ++f) pr[16 + f] = h3[f];
    }
}

// ---------------------------------------------------------------------------
// Kernel 2: pre-permute w_out to the signature's lane-coalesced channel order.
// perm: c' in [0,420) identity; s3 blocks transposed (k,lane) <-> (lane-as-j,k)
// ---------------------------------------------------------------------------
__global__ __launch_bounds__(256) void k_permw(const float* __restrict__ w_out,
                                               float* __restrict__ w_perm)
{
    int idx = blockIdx.x * 256 + threadIdx.x;     // exactly 128*8420
    int o   = idx / SIGCH;
    int cp  = idx - o * SIGCH;
    int c;
    if (cp < 420) {
        c = cp;                                    // s1 + s2 (identity: p = q*64+lane)
    } else if (cp < 8100) {
        int id = cp - 420; int q = id / 1280; int r = id - q * 1280;
        int k = r >> 6; int ln = r & 63;
        c = 420 + q * 1280 + ln * 20 + k;
    } else {
        int id = cp - 8100; int k = id >> 4; int ln = id & 15;
        c = 8100 + ln * 20 + k;
    }
    w_perm[idx] = w_out[(size_t)o * SIGCH + c];
}

// ---------------------------------------------------------------------------
// Kernel 3: depth-3 signature. One wave per batch element. block = 4 waves.
// lane owns pairs p = lane + 64q (q<7, p<400): s2[p] + s3[p][0..19] in VGPRs.
// Per step: s3[p][k] += (s2[p] + 0.5*s1[i]*dj + di*dj/6) * d[k]  (single FMA/elt)
// ---------------------------------------------------------------------------
__global__ __launch_bounds__(256) void k_signature(const float* __restrict__ path,
                                                   float* __restrict__ sig)
{
    __shared__ float incs[4][620];
    __shared__ float s1s[4][20];
    const int tid  = threadIdx.x;
    const int lane = tid & 63;
    const int w    = tid >> 6;
    const int b    = blockIdx.x * 4 + w;
    const float* pb = path + (size_t)b * 620;

    for (int i = lane; i < 620; i += 64) {
        float cur  = pb[i];
        float prev = (i >= 20) ? pb[i - 20] : 0.f;
        incs[w][i] = cur - prev;
    }
    if (lane < 20) s1s[w][lane] = 0.f;
    __syncthreads();

    int iv[7], jv[7];
#pragma unroll
    for (int q = 0; q < 7; ++q) {
        int p = lane + 64 * q;
        iv[q] = p / 20; jv[q] = p - iv[q] * 20;
    }
    float s2r[7];
    float s3r[7][20];
#pragma unroll
    for (int q = 0; q < 7; ++q) {
        s2r[q] = 0.f;
#pragma unroll
        for (int k = 0; k < 20; ++k) s3r[q][k] = 0.f;
    }

    for (int t = 0; t < LP; ++t) {
        float dreg[20];
        const float4* dp = (const float4*)(&incs[w][t * 20]);
#pragma unroll
        for (int r = 0; r < 5; ++r) {
            float4 v = dp[r];
            dreg[4 * r] = v.x; dreg[4 * r + 1] = v.y; dreg[4 * r + 2] = v.z; dreg[4 * r + 3] = v.w;
        }
#pragma unroll
        for (int q = 0; q < 7; ++q) {
            if (lane + 64 * q < 400) {
                const float di  = incs[w][t * 20 + iv[q]];
                const float dj  = incs[w][t * 20 + jv[q]];
                const float s1i = s1s[w][iv[q]];
                const float t2  = s2r[q] + (0.5f * s1i + (1.0f / 6.0f) * di) * dj;
#pragma unroll
                for (int k = 0; k < 20; ++k) s3r[q][k] += t2 * dreg[k];
                s2r[q] += (s1i + 0.5f * di) * dj;
            }
        }
        __syncthreads();
        if (lane < 20) s1s[w][lane] += incs[w][t * 20 + lane];
        __syncthreads();
    }

    float* sg = sig + (size_t)b * SIGCH;
    if (lane < 20) sg[lane] = s1s[w][lane];
#pragma unroll
    for (int q = 0; q < 6; ++q) sg[20 + q * 64 + lane] = s2r[q];   // identity order
    if (lane < 16) sg[404 + lane] = s2r[6];
#pragma unroll
    for (int q = 0; q < 6; ++q) {
#pragma unroll
        for (int k = 0; k < 20; ++k)
            sg[420 + q * 1280 + k * 64 + lane] = s3r[q][k];        // coalesced
    }
    if (lane < 16) {
#pragma unroll
        for (int k = 0; k < 20; ++k)
            sg[8100 + k * 16 + lane] = s3r[6][k];
    }
}

// ---------------------------------------------------------------------------
// Kernel 4: fp32 GEMM  z[2048][128] = sig[2048][8420] x w_perm^T, split-K=16.
// block = 256 thr, tile M64 x N128, micro 4x8 (b128 LDS reads -> FMA-bound).
// grid = 32 mtiles * 16 splits = 512 blocks (2/CU).
// ---------------------------------------------------------------------------
__global__ __launch_bounds__(256) void k_gemm(const float* __restrict__ sig,
                                              const float* __restrict__ w_perm,
                                              float* __restrict__ z_part)
{
    __shared__ float sigS[32][68];
    __shared__ float wS[32][132];
    const int tid = threadIdx.x;
    const int mt  = blockIdx.x >> 4;
    const int s   = blockIdx.x & 15;
    const int m0  = mt * 64;
    const int kb  = s * KLEN;
    const int ke  = (kb + KLEN < SIGCH) ? (kb + KLEN) : SIGCH;
    const int tx  = tid & 15;    // n = tx*8
    const int ty  = tid >> 4;    // m = ty*4

    float acc[4][8];
#pragma unroll
    for (int i = 0; i < 4; ++i) {
#pragma unroll
        for (int j = 0; j < 8; ++j) acc[i][j] = 0.f;
    }

    const int lrow = tid >> 3;          // 0..31
    const int lcq  = (tid & 7) * 4;     // 0,4,...,28

    for (int c0 = kb; c0 < ke; c0 += 32) {
#pragma unroll
        for (int r = 0; r < 2; ++r) {   // sig tile: 64 rows x 32 k
            int row = lrow + r * 32;
            int c   = c0 + lcq;
            float4 v = make_float4(0.f, 0.f, 0.f, 0.f);
            if (c < ke) v = *(const float4*)(sig + (size_t)(m0 + row) * SIGCH + c);
            sigS[lcq + 0][row] = v.x; sigS[lcq + 1][row] = v.y;
            sigS[lcq + 2][row] = v.z; sigS[lcq + 3][row] = v.w;
        }
#pragma unroll
        for (int r = 0; r < 4; ++r) {   // w tile: 128 rows x 32 k
            int o = lrow + r * 32;
            int c = c0 + lcq;
            float4 v = make_float4(0.f, 0.f, 0.f, 0.f);
            if (c < ke) v = *(const float4*)(w_perm + (size_t)o * SIGCH + c);
            wS[lcq + 0][o] = v.x; wS[lcq + 1][o] = v.y;
            wS[lcq + 2][o] = v.z; wS[lcq + 3][o] = v.w;
        }
        __syncthreads();
#pragma unroll 8
        for (int k = 0; k < 32; ++k) {
            float4 a  = *(const float4*)(&sigS[k][ty * 4]);
            float4 bA = *(const float4*)(&wS[k][tx * 8]);
            float4 bB = *(const float4*)(&wS[k][tx * 8 + 4]);
            float av[4] = {a.x, a.y, a.z, a.w};
            float bv[8] = {bA.x, bA.y, bA.z, bA.w, bB.x, bB.y, bB.z, bB.w};
#pragma unroll
            for (int i = 0; i < 4; ++i) {
#pragma unroll
                for (int j = 0; j < 8; ++j) acc[i][j] += av[i] * bv[j];
            }
        }
        __syncthreads();
    }

#pragma unroll
    for (int i = 0; i < 4; ++i) {
        size_t base = ((size_t)s * B_TOT + (m0 + ty * 4 + i)) * NOUT + tx * 8;
        *(float4*)(z_part + base)     = make_float4(acc[i][0], acc[i][1], acc[i][2], acc[i][3]);
        *(float4*)(z_part + base + 4) = make_float4(acc[i][4], acc[i][5], acc[i][6], acc[i][7]);
    }
}

// ---------------------------------------------------------------------------
// Kernel 5: reduce split-K partials, add bias, softplus on second half.
// out layout: mean (2048*64) then std (2048*64).
// ---------------------------------------------------------------------------
__global__ __launch_bounds__(256) void k_final(const float* __restrict__ z_part,
                                               const float* __restrict__ b_out,
                                               float* __restrict__ out)
{
    int idx = blockIdx.x * 256 + threadIdx.x;   // 2048*128
    int b = idx >> 7;
    int o = idx & 127;
    float z = b_out[o];
#pragma unroll
    for (int s = 0; s < KSPLIT; ++s) z += z_part[((size_t)s * B_TOT + b) * NOUT + o];
    if (o < 64) {
        out[(size_t)b * 64 + o] = z;
    } else {
        float sp = fmaxf(z, 0.f) + log1pf(expf(-fabsf(z)));
        out[131072 + (size_t)b * 64 + (o - 64)] = sp;
    }
}

// ---------------------------------------------------------------------------
extern "C" void kernel_launch(void* const* d_in, const int* in_sizes, int n_in,
                              void* d_out, int out_size, void* d_ws, size_t ws_size,
                              hipStream_t stream)
{
    const float* x     = (const float*)d_in[0];
    // d_in[1] observed_tp is unused by the reference computation
    const float* w1    = (const float*)d_in[2];
    const float* b1    = (const float*)d_in[3];
    const float* w2    = (const float*)d_in[4];
    const float* b2    = (const float*)d_in[5];
    const float* w3    = (const float*)d_in[6];
    const float* b3    = (const float*)d_in[7];
    const float* w_out = (const float*)d_in[8];
    const float* b_out = (const float*)d_in[9];
    float* out = (float*)d_out;

    float* ws    = (float*)d_ws;
    float* path  = ws;                               // 2048*620      = 1,269,760 f
    float* sig   = ws + 1269760;                     // 2048*8420     = 17,244,160 f
    float* wperm = ws + 1269760 + 17244160;          // 128*8420      = 1,077,760 f
    float* zpart = ws + 19591680;                    // 16*2048*128   = 4,194,304 f
    // total = 23,785,984 floats = ~95.1 MB of workspace

    hipLaunchKernelGGL(k_augment,   dim3(512),  dim3(128), 0, stream,
                       x, w1, b1, w2, b2, w3, b3, path);
    hipLaunchKernelGGL(k_permw,     dim3(4210), dim3(256), 0, stream, w_out, wperm);
    hipLaunchKernelGGL(k_signature, dim3(512),  dim3(256), 0, stream, path, sig);
    hipLaunchKernelGGL(k_gemm,      dim3(512),  dim3(256), 0, stream, sig, wperm, zpart);
    hipLaunchKernelGGL(k_final,     dim3(1024), dim3(256), 0, stream, zpart, b_out, out);
}

// Round 3
// 161.943 us; speedup vs baseline: 1.3969x; 1.3969x over previous
//
#include <hip/hip_runtime.h>
#include <math.h>

#define B_TOT 2048
#define D_INC 15
#define KW    40
#define CCH   20
#define LP    31
#define SIGCH 8420
#define SIGP  8448   // padded K (zeros in [8420,8448)); 8448 = 8*1056 = 264*32
#define NOUT  128
#define KSPLIT 8
#define KLEN  1056   // per-split K (33 chunks of 32)

typedef _Float16 f16;
typedef _Float16 f16x8 __attribute__((ext_vector_type(8)));
typedef _Float16 f16x4 __attribute__((ext_vector_type(4)));
typedef float    f32x4 __attribute__((ext_vector_type(4)));

// ---------------------------------------------------------------------------
// Kernel 1: augment. 256 thr = 16 hid x 4 pos-quarter x 4 batch. grid 512.
// LDS ~57 KB -> 2 blocks/CU = 2 waves/SIMD.
// ---------------------------------------------------------------------------
__global__ __launch_bounds__(256) void k_augment(
    const float* __restrict__ x,  const float* __restrict__ w1, const float* __restrict__ b1,
    const float* __restrict__ w2, const float* __restrict__ b2,
    const float* __restrict__ w3, const float* __restrict__ b3,
    float* __restrict__ path)
{
    __shared__ float xs[4 * 1068];
    __shared__ float w1s[9600];             // [m][h], m=c*40+k ; aliased by h1s later
    __shared__ float wsmall[356];
    float* w2s = wsmall;        float* b2s = wsmall + 256;
    float* w3s = wsmall + 272;  float* b3s = wsmall + 336;
    float* b1s = wsmall + 340;
    float* h1s = w1s;                       // alias after barrier (124*17=2108)

    const int tid = threadIdx.x;
    const int b0  = blockIdx.x * 4;

    for (int i = tid; i < 4 * 1050; i += 256) {
        int bl = i / 1050; int t = i - bl * 1050;
        xs[bl * 1068 + t] = x[(size_t)b0 * 1050 + i];
    }
    for (int i = tid; i < 9600; i += 256) {
        int h = i / 600; int m = i - h * 600;
        w1s[m * 16 + h] = w1[i];
    }
    if (tid < 256) w2s[tid] = w2[tid];
    if (tid < 16)  b2s[tid] = b2[tid];
    if (tid < 64)  w3s[tid] = w3[tid];
    if (tid < 4)   b3s[tid] = b3[tid];
    if (tid < 16)  b1s[tid] = b1[tid];
    __syncthreads();

    const int h     = tid & 15;
    const int qr    = (tid >> 4) & 3;
    const int bl    = tid >> 6;
    const int pbase = qr * 8;

    float acc[8];
#pragma unroll
    for (int p = 0; p < 8; ++p) acc[p] = 0.f;

    for (int c = 0; c < D_INC; ++c) {
        float xcol[47];
        const int base = bl * 1068 + pbase * 15 + c;
#pragma unroll
        for (int i = 0; i < 47; ++i) xcol[i] = xs[base + i * 15];
#pragma unroll
        for (int k = 0; k < KW; ++k) {
            const float wv = w1s[(c * 40 + k) * 16 + h];
#pragma unroll
            for (int p = 0; p < 8; ++p) acc[p] += xcol[p + k] * wv;
        }
    }
    __syncthreads();            // all w1s reads done before alias write
    const float bb1 = b1s[h];
#pragma unroll
    for (int p = 0; p < 8; ++p) {
        int pos = pbase + p;
        if (pos < LP) h1s[(bl * 31 + pos) * 17 + h] = fmaxf(acc[p] + bb1, 0.f);
    }
    __syncthreads();

    if (tid < 124) {            // 4 batches * 31 positions
        const int bl2 = tid / 31;
        const int pos = tid - bl2 * 31;
        float hr[16];
#pragma unroll
        for (int c2 = 0; c2 < 16; ++c2) hr[c2] = h1s[tid * 17 + c2];
        float h2[16];
#pragma unroll
        for (int o = 0; o < 16; ++o) {
            float s = b2s[o];
#pragma unroll
            for (int c2 = 0; c2 < 16; ++c2) s += w2s[o * 16 + c2] * hr[c2];
            h2[o] = fmaxf(s, 0.f);
        }
        float h3[4];
#pragma unroll
        for (int f = 0; f < 4; ++f) {
            float s = b3s[f];
#pragma unroll
            for (int c2 = 0; c2 < 16; ++c2) s += w3s[f * 16 + c2] * h2[c2];
            h3[f] = s;
        }
        float* pr = path + ((size_t)(b0 + bl2) * LP + pos) * CCH;
#pragma unroll
        for (int d = 0; d < D_INC; ++d) pr[d] = xs[bl2 * 1068 + (pos + 39) * 15 + d];
        pr[15] = (float)pos * (1.0f / 30.0f);
#pragma unroll
        for (int f = 0; f < 4; ++f) pr[16 + f] = h3[f];
    }
}

// ---------------------------------------------------------------------------
// Kernel 2: convert w_out fp32 -> fp16, pad K to 8448 with zeros.
// ---------------------------------------------------------------------------
__global__ __launch_bounds__(256) void k_convw(const float* __restrict__ w_out,
                                               f16* __restrict__ wh)
{
    int idx = blockIdx.x * 256 + threadIdx.x;     // 128*8448 exactly
    int o   = idx / SIGP;
    int c   = idx - o * SIGP;
    wh[idx] = (c < SIGCH) ? (f16)w_out[(size_t)o * SIGCH + c] : (f16)0.f;
}

// ---------------------------------------------------------------------------
// Kernel 3: depth-3 signature, barrier-free t-loop.
// s1 before step t == path[t-1] (path[-1]=0) -> read from zero-prepended copy.
// One wave per batch; lane owns pairs p = lane+64q; outputs fp16 natural order.
// ---------------------------------------------------------------------------
__global__ __launch_bounds__(256) void k_signature(const float* __restrict__ path,
                                                   f16* __restrict__ sig)
{
    __shared__ float pprev[4][656];   // [0..19]=0, [20..639] = path row-major
    __shared__ float incs[4][624];    // increments (diff with prepend-zero)
    const int tid  = threadIdx.x;
    const int lane = tid & 63;
    const int w    = tid >> 6;
    const int b    = blockIdx.x * 4 + w;
    const float* pb = path + (size_t)b * 620;

    for (int i = lane; i < 620; i += 64) {
        float cur  = pb[i];
        float prev = (i >= 20) ? pb[i - 20] : 0.f;
        pprev[w][20 + i] = cur;
        incs[w][i] = cur - prev;
    }
    if (lane < 20) pprev[w][lane] = 0.f;
    __syncthreads();

    int iv[7], jv[7];
#pragma unroll
    for (int q = 0; q < 7; ++q) {
        int p = lane + 64 * q;
        iv[q] = p / 20; jv[q] = p - iv[q] * 20;
    }
    float s2r[7];
    float s3r[7][20];
#pragma unroll
    for (int q = 0; q < 7; ++q) {
        s2r[q] = 0.f;
#pragma unroll
        for (int k = 0; k < 20; ++k) s3r[q][k] = 0.f;
    }

    for (int t = 0; t < LP; ++t) {
        const float* ip = &incs[w][t * 20];
        const float* sp = &pprev[w][t * 20];
        float dreg[20];
        const float4* dp = (const float4*)ip;
#pragma unroll
        for (int r = 0; r < 5; ++r) {
            float4 v = dp[r];
            dreg[4 * r] = v.x; dreg[4 * r + 1] = v.y; dreg[4 * r + 2] = v.z; dreg[4 * r + 3] = v.w;
        }
#pragma unroll
        for (int q = 0; q < 7; ++q) {
            if (lane + 64 * q < 400) {
                const float di  = ip[iv[q]];
                const float dj  = ip[jv[q]];
                const float s1i = sp[iv[q]];            // s1 BEFORE this step
                const float t2  = s2r[q] + (0.5f * s1i + (1.0f / 6.0f) * di) * dj;
#pragma unroll
                for (int k = 0; k < 20; ++k) s3r[q][k] += t2 * dreg[k];
                s2r[q] += (s1i + 0.5f * di) * dj;
            }
        }
    }

    f16* sg = sig + (size_t)b * SIGP;
    if (lane < 20) sg[lane] = (f16)pprev[w][620 + lane];     // s1 = path[30]
#pragma unroll
    for (int q = 0; q < 6; ++q) sg[20 + q * 64 + lane] = (f16)s2r[q];
    if (lane < 16) sg[404 + lane] = (f16)s2r[6];
#pragma unroll
    for (int q = 0; q < 7; ++q) {
        int p = lane + 64 * q;
        if (p < 400) {
            f16* base = sg + 420 + p * 20;                   // byte off 840+40p: 8-aligned
#pragma unroll
            for (int g = 0; g < 5; ++g) {
                f16x4 v = { (f16)s3r[q][4 * g],     (f16)s3r[q][4 * g + 1],
                            (f16)s3r[q][4 * g + 2], (f16)s3r[q][4 * g + 3] };
                *(f16x4*)(base + 4 * g) = v;
            }
        }
    }
    if (lane < 28) sg[SIGCH + lane] = (f16)0.f;              // zero the K pad
}

// ---------------------------------------------------------------------------
// Kernel 4: fp16 MFMA GEMM  z[2048][128] = sig x wh^T. BM32/BN128/BK32,
// split-K 8. grid = 64 mtiles x 8 splits = 512 blocks (2/CU). 4 waves:
// wave w covers n in [32w,32w+32); per chunk 2x2 mfma_f32_16x16x32_f16.
// LDS [kg][row][8] layout -> conflict-free b128 frag reads.
// ---------------------------------------------------------------------------
__global__ __launch_bounds__(256) void k_gemm(const f16* __restrict__ sigh,
                                              const f16* __restrict__ wh,
                                              float* __restrict__ z_part)
{
    __shared__ f16 As[4 * 32 * 8];     // 2 KB
    __shared__ f16 Bs[4 * 128 * 8];    // 8 KB
    const int tid = threadIdx.x;
    const int l   = tid & 63;
    const int wv  = tid >> 6;
    const int mt  = blockIdx.x >> 3;
    const int s   = blockIdx.x & 7;
    const int m0  = mt * 32;
    const int kb  = s * KLEN;

    const f32x4 z4 = {0.f, 0.f, 0.f, 0.f};
    f32x4 acc[2][2];
    acc[0][0] = z4; acc[0][1] = z4; acc[1][0] = z4; acc[1][1] = z4;

    // staging maps: A slot = tid (tid<128): kg=tid>>5, m=tid&31
    //               B slot = r*256+tid:     kg=slot>>7, n=slot&127
    const size_t gA = (size_t)(m0 + (tid & 31)) * SIGP + (tid >> 5) * 8;
    const size_t gB0 = (size_t)(tid & 127) * SIGP + (tid >> 7) * 8;            // r=0
    const size_t gB1 = (size_t)((256 + tid) & 127) * SIGP + ((256 + tid) >> 7) * 8; // r=1

    f16x8 aR = {}, bR0, bR1;
    if (tid < 128) aR = *(const f16x8*)(sigh + gA + kb);
    bR0 = *(const f16x8*)(wh + gB0 + kb);
    bR1 = *(const f16x8*)(wh + gB1 + kb);

    const int kg   = l >> 4;
    const int mrow = l & 15;

    for (int ch = 0; ch < 33; ++ch) {
        if (tid < 128) *(f16x8*)&As[tid * 8] = aR;
        *(f16x8*)&Bs[tid * 8] = bR0;
        *(f16x8*)&Bs[(256 + tid) * 8] = bR1;
        __syncthreads();

        if (ch < 32) {                       // prefetch next chunk
            int k1 = kb + (ch + 1) * 32;
            if (tid < 128) aR = *(const f16x8*)(sigh + gA + k1);
            bR0 = *(const f16x8*)(wh + gB0 + k1);
            bR1 = *(const f16x8*)(wh + gB1 + k1);
        }

        f16x8 aF[2], bF[2];
#pragma unroll
        for (int m2 = 0; m2 < 2; ++m2)
            aF[m2] = *(const f16x8*)&As[(kg * 32 + m2 * 16 + mrow) * 8];
#pragma unroll
        for (int n2 = 0; n2 < 2; ++n2)
            bF[n2] = *(const f16x8*)&Bs[(kg * 128 + wv * 32 + n2 * 16 + mrow) * 8];
#pragma unroll
        for (int m2 = 0; m2 < 2; ++m2)
#pragma unroll
            for (int n2 = 0; n2 < 2; ++n2)
                acc[m2][n2] = __builtin_amdgcn_mfma_f32_16x16x32_f16(aF[m2], bF[n2], acc[m2][n2], 0, 0, 0);
        __syncthreads();
    }

    // C/D layout: col = l&15, row = (l>>4)*4 + reg   [m89-verified]
#pragma unroll
    for (int m2 = 0; m2 < 2; ++m2) {
#pragma unroll
        for (int n2 = 0; n2 < 2; ++n2) {
            int n = wv * 32 + n2 * 16 + (l & 15);
#pragma unroll
            for (int r = 0; r < 4; ++r) {
                int m = m0 + m2 * 16 + (l >> 4) * 4 + r;
                z_part[((size_t)s * B_TOT + m) * NOUT + n] = acc[m2][n2][r];
            }
        }
    }
}

// ---------------------------------------------------------------------------
// Kernel 5: reduce split-K partials, add bias, softplus on second half.
// ---------------------------------------------------------------------------
__global__ __launch_bounds__(256) void k_final(const float* __restrict__ z_part,
                                               const float* __restrict__ b_out,
                                               float* __restrict__ out)
{
    int idx = blockIdx.x * 256 + threadIdx.x;   // 2048*128
    int b = idx >> 7;
    int o = idx & 127;
    float z = b_out[o];
#pragma unroll
    for (int s = 0; s < KSPLIT; ++s) z += z_part[((size_t)s * B_TOT + b) * NOUT + o];
    if (o < 64) {
        out[(size_t)b * 64 + o] = z;
    } else {
        float sp = fmaxf(z, 0.f) + log1pf(expf(-fabsf(z)));
        out[131072 + (size_t)b * 64 + (o - 64)] = sp;
    }
}

// ---------------------------------------------------------------------------
extern "C" void kernel_launch(void* const* d_in, const int* in_sizes, int n_in,
                              void* d_out, int out_size, void* d_ws, size_t ws_size,
                              hipStream_t stream)
{
    const float* x     = (const float*)d_in[0];
    const float* w1    = (const float*)d_in[2];
    const float* b1    = (const float*)d_in[3];
    const float* w2    = (const float*)d_in[4];
    const float* b2    = (const float*)d_in[5];
    const float* w3    = (const float*)d_in[6];
    const float* b3    = (const float*)d_in[7];
    const float* w_out = (const float*)d_in[8];
    const float* b_out = (const float*)d_in[9];
    float* out = (float*)d_out;

    float* ws   = (float*)d_ws;
    float* path = ws;                                  // 2048*620        = 1,269,760 f
    f16*   sigh = (f16*)(ws + 1269760);                // 2048*8448 f16   = 8,650,752 f
    f16*   wh   = (f16*)(ws + 9920512);                // 128*8448 f16    =   540,672 f
    float* zpart = ws + 10461184;                      // 8*2048*128      = 2,097,152 f
    // total 12,558,336 floats ~= 50.2 MB

    hipLaunchKernelGGL(k_augment,   dim3(512),  dim3(256), 0, stream,
                       x, w1, b1, w2, b2, w3, b3, path);
    hipLaunchKernelGGL(k_convw,     dim3(4224), dim3(256), 0, stream, w_out, wh);
    hipLaunchKernelGGL(k_signature, dim3(512),  dim3(256), 0, stream, path, sigh);
    hipLaunchKernelGGL(k_gemm,      dim3(512),  dim3(256), 0, stream, sigh, wh, zpart);
    hipLaunchKernelGGL(k_final,     dim3(1024), dim3(256), 0, stream, zpart, b_out, out);
}

// Round 4
// 158.634 us; speedup vs baseline: 1.4260x; 1.0209x over previous
//
#include <hip/hip_runtime.h>
#include <math.h>

#define B_TOT 2048
#define D_INC 15
#define KW    40
#define CCH   20
#define LP    31
#define SIGCH 8420
#define SIGP  8448   // padded K; 8448 = 11*768, 768 = 12*64
#define NOUT  128
#define KSPLIT 11
#define KLEN  768    // per-split K: 12 chunks of BK=64

typedef _Float16 f16;
typedef _Float16 f16x8 __attribute__((ext_vector_type(8)));
typedef _Float16 f16x4 __attribute__((ext_vector_type(4)));
typedef float    f32x4 __attribute__((ext_vector_type(4)));

// ---------------------------------------------------------------------------
// Kernel 1: fused augment + signature (+ w_out fp32->fp16 convert on 32 side
// blocks). Blocks 0..511: 4 batches each, 256 thr. path never leaves LDS.
// LDS: xs(17.1K) + w1s(38.4K, aliased: h1s / pprev / incs) + wsmall = 56.9 KB.
// ---------------------------------------------------------------------------
__global__ __launch_bounds__(256) void k_augsig(
    const float* __restrict__ x,  const float* __restrict__ w1, const float* __restrict__ b1,
    const float* __restrict__ w2, const float* __restrict__ b2,
    const float* __restrict__ w3, const float* __restrict__ b3,
    const float* __restrict__ w_out, f16* __restrict__ wh, f16* __restrict__ sig)
{
    if (blockIdx.x >= 512) {
        // ---- convw: 32 blocks convert w_out (128x8420 fp32) -> wh (128x8448 f16)
        int t0 = (blockIdx.x - 512) * 256 + threadIdx.x;     // 8192 threads
        for (int chunk = t0; chunk < 128 * 1056; chunk += 8192) {
            int o  = chunk / 1056;
            int cw = chunk - o * 1056;
            int c0 = cw * 8;
            f16x8 v;
            if (c0 + 8 <= SIGCH) {
                const float* src = w_out + (size_t)o * SIGCH + c0;
                float4 a = *(const float4*)src;
                float4 b = *(const float4*)(src + 4);
                v = (f16x8){(f16)a.x,(f16)a.y,(f16)a.z,(f16)a.w,
                            (f16)b.x,(f16)b.y,(f16)b.z,(f16)b.w};
            } else {
#pragma unroll
                for (int e = 0; e < 8; ++e) {
                    int c = c0 + e;
                    v[e] = (c < SIGCH) ? (f16)w_out[(size_t)o * SIGCH + c] : (f16)0.f;
                }
            }
            *(f16x8*)(wh + (size_t)o * SIGP + c0) = v;
        }
        return;
    }

    __shared__ float xs[4 * 1068];
    __shared__ float w1s[9600];          // conv weights [m][h]; then aliased
    __shared__ float wsmall[356];
    float* w2s = wsmall;        float* b2s = wsmall + 256;
    float* w3s = wsmall + 272;  float* b3s = wsmall + 336;
    float* b1s = wsmall + 340;
    float* h1s   = w1s;                  // 2108 floats   (alias, after barrier)
    float* pprev = w1s + 2624;           // 4*656 = 2624  (zero-prepended path)
    float* incs  = w1s + 5248;           // 4*624 = 2496  (total 7744 < 9600)

    const int tid = threadIdx.x;
    const int b0  = blockIdx.x * 4;

    for (int i = tid; i < 4 * 1050; i += 256) {
        int bl = i / 1050; int t = i - bl * 1050;
        xs[bl * 1068 + t] = x[(size_t)b0 * 1050 + i];
    }
    for (int i = tid; i < 9600; i += 256) {
        int h = i / 600; int m = i - h * 600;
        w1s[m * 16 + h] = w1[i];
    }
    if (tid < 256) w2s[tid] = w2[tid];
    if (tid < 16)  b2s[tid] = b2[tid];
    if (tid < 64)  w3s[tid] = w3[tid];
    if (tid < 4)   b3s[tid] = b3[tid];
    if (tid < 16)  b1s[tid] = b1[tid];
    __syncthreads();

    // ---- conv1d: 16 hid x 4 pos-quarter x 4 batch
    {
        const int h     = tid & 15;
        const int qr    = (tid >> 4) & 3;
        const int bl    = tid >> 6;
        const int pbase = qr * 8;
        float acc[8];
#pragma unroll
        for (int p = 0; p < 8; ++p) acc[p] = 0.f;
        for (int c = 0; c < D_INC; ++c) {
            float xcol[47];
            const int base = bl * 1068 + pbase * 15 + c;
#pragma unroll
            for (int i = 0; i < 47; ++i) xcol[i] = xs[base + i * 15];
#pragma unroll
            for (int k = 0; k < KW; ++k) {
                const float wv = w1s[(c * 40 + k) * 16 + h];
#pragma unroll
                for (int p = 0; p < 8; ++p) acc[p] += xcol[p + k] * wv;
            }
        }
        __syncthreads();          // all w1s reads done before alias write
        const float bb1 = b1s[h];
#pragma unroll
        for (int p = 0; p < 8; ++p) {
            int pos = pbase + p;
            if (pos < LP) h1s[(bl * 31 + pos) * 17 + h] = fmaxf(acc[p] + bb1, 0.f);
        }
        __syncthreads();
    }

    // ---- small MLPs; write path rows directly into pprev (LDS)
    if (tid < 124) {
        const int bl2 = tid / 31;
        const int pos = tid - bl2 * 31;
        float hr[16];
#pragma unroll
        for (int c2 = 0; c2 < 16; ++c2) hr[c2] = h1s[tid * 17 + c2];
        float h2[16];
#pragma unroll
        for (int o = 0; o < 16; ++o) {
            float s = b2s[o];
#pragma unroll
            for (int c2 = 0; c2 < 16; ++c2) s += w2s[o * 16 + c2] * hr[c2];
            h2[o] = fmaxf(s, 0.f);
        }
        float h3[4];
#pragma unroll
        for (int f = 0; f < 4; ++f) {
            float s = b3s[f];
#pragma unroll
            for (int c2 = 0; c2 < 16; ++c2) s += w3s[f * 16 + c2] * h2[c2];
            h3[f] = s;
        }
        float* pr = pprev + bl2 * 656 + 20 + pos * 20;
#pragma unroll
        for (int d = 0; d < D_INC; ++d) pr[d] = xs[bl2 * 1068 + (pos + 39) * 15 + d];
        pr[15] = (float)pos * (1.0f / 30.0f);
#pragma unroll
        for (int f = 0; f < 4; ++f) pr[16 + f] = h3[f];
    } else {
        int z = tid - 124;                         // zero the prepend rows
        if (z < 80) pprev[(z / 20) * 656 + (z % 20)] = 0.f;
    }
    __syncthreads();

    // ---- signature phase (identical algebra to green round-3 kernel)
    const int lane = tid & 63;
    const int w    = tid >> 6;
    const int b    = b0 + w;
    float* pp = pprev + w * 656;
    float* ic = incs  + w * 624;

    for (int i = lane; i < 620; i += 64) ic[i] = pp[20 + i] - pp[i];
    __syncthreads();

    int iv[7], jv[7];
#pragma unroll
    for (int q = 0; q < 7; ++q) {
        int p = lane + 64 * q;
        iv[q] = p / 20; jv[q] = p - iv[q] * 20;
    }
    float s2r[7];
    float s3r[7][20];
#pragma unroll
    for (int q = 0; q < 7; ++q) {
        s2r[q] = 0.f;
#pragma unroll
        for (int k = 0; k < 20; ++k) s3r[q][k] = 0.f;
    }

    for (int t = 0; t < LP; ++t) {
        const float* ip = &ic[t * 20];
        const float* sp = &pp[t * 20];              // s1 before step t
        float dreg[20];
        const float4* dp = (const float4*)ip;
#pragma unroll
        for (int r = 0; r < 5; ++r) {
            float4 v = dp[r];
            dreg[4*r] = v.x; dreg[4*r+1] = v.y; dreg[4*r+2] = v.z; dreg[4*r+3] = v.w;
        }
#pragma unroll
        for (int q = 0; q < 7; ++q) {
            if (lane + 64 * q < 400) {
                const float di  = ip[iv[q]];
                const float dj  = ip[jv[q]];
                const float s1i = sp[iv[q]];
                const float t2  = s2r[q] + (0.5f * s1i + (1.0f / 6.0f) * di) * dj;
#pragma unroll
                for (int k = 0; k < 20; ++k) s3r[q][k] += t2 * dreg[k];
                s2r[q] += (s1i + 0.5f * di) * dj;
            }
        }
    }

    f16* sg = sig + (size_t)b * SIGP;
    if (lane < 20) sg[lane] = (f16)pp[620 + lane];          // s1 = path[30]
#pragma unroll
    for (int q = 0; q < 6; ++q) sg[20 + q * 64 + lane] = (f16)s2r[q];
    if (lane < 16) sg[404 + lane] = (f16)s2r[6];
#pragma unroll
    for (int q = 0; q < 7; ++q) {
        int p = lane + 64 * q;
        if (p < 400) {
            f16* base = sg + 420 + p * 20;                  // 8-byte aligned
#pragma unroll
            for (int g = 0; g < 5; ++g) {
                f16x4 v = { (f16)s3r[q][4*g],   (f16)s3r[q][4*g+1],
                            (f16)s3r[q][4*g+2], (f16)s3r[q][4*g+3] };
                *(f16x4*)(base + 4 * g) = v;
            }
        }
    }
    if (lane < 28) sg[SIGCH + lane] = (f16)0.f;             // zero K pad
}

// ---------------------------------------------------------------------------
// Kernel 2: fp16 MFMA GEMM, BM32/BN128/BK64, split-K 11 (12 iters of 64).
// grid = 64 mtiles x 11 splits = 704 blocks (~2.75/CU). 8 MFMA per barrier.
// LDS [g][row][8] (g = kc*4+kg) -> linear staging slots, conflict-light.
// ---------------------------------------------------------------------------
__global__ __launch_bounds__(256) void k_gemm(const f16* __restrict__ sigh,
                                              const f16* __restrict__ wh,
                                              float* __restrict__ z_part)
{
    __shared__ f16 As[2048];    // 4 KB : 8 g-groups x 32 m x 8
    __shared__ f16 Bs[8192];    // 16 KB: 8 g-groups x 128 n x 8
    const int tid = threadIdx.x;
    const int l   = tid & 63;
    const int wv  = tid >> 6;
    const int mt  = blockIdx.x / KSPLIT;
    const int s   = blockIdx.x - mt * KSPLIT;
    const int m0  = mt * 32;
    const int kb  = s * KLEN;

    const f32x4 z4 = {0.f, 0.f, 0.f, 0.f};
    f32x4 acc[2][2];
    acc[0][0] = z4; acc[0][1] = z4; acc[1][0] = z4; acc[1][1] = z4;

    // staging: A slot tid -> row tid&31, kgrp tid>>5 ; B slot r*256+tid
    const size_t gA = (size_t)(m0 + (tid & 31)) * SIGP + kb + (tid >> 5) * 8;
    size_t gB[4];
#pragma unroll
    for (int r = 0; r < 4; ++r) {
        int slot = r * 256 + tid;
        gB[r] = (size_t)(slot & 127) * SIGP + kb + (slot >> 7) * 8;
    }

    f16x8 aR = *(const f16x8*)(sigh + gA);
    f16x8 bR[4];
#pragma unroll
    for (int r = 0; r < 4; ++r) bR[r] = *(const f16x8*)(wh + gB[r]);

    const int kg   = l >> 4;
    const int mrow = l & 15;

    for (int ch = 0; ch < 12; ++ch) {
        *(f16x8*)&As[tid * 8] = aR;
#pragma unroll
        for (int r = 0; r < 4; ++r) *(f16x8*)&Bs[(r * 256 + tid) * 8] = bR[r];
        __syncthreads();

        if (ch < 11) {                     // prefetch next BK=64 chunk
            int koff = (ch + 1) * 64;
            aR = *(const f16x8*)(sigh + gA + koff);
#pragma unroll
            for (int r = 0; r < 4; ++r) bR[r] = *(const f16x8*)(wh + gB[r] + koff);
        }

#pragma unroll
        for (int kc = 0; kc < 2; ++kc) {
            f16x8 aF[2], bF[2];
#pragma unroll
            for (int m2 = 0; m2 < 2; ++m2)
                aF[m2] = *(const f16x8*)&As[((kc * 4 + kg) * 32 + m2 * 16 + mrow) * 8];
#pragma unroll
            for (int n2 = 0; n2 < 2; ++n2)
                bF[n2] = *(const f16x8*)&Bs[((kc * 4 + kg) * 128 + wv * 32 + n2 * 16 + mrow) * 8];
#pragma unroll
            for (int m2 = 0; m2 < 2; ++m2)
#pragma unroll
                for (int n2 = 0; n2 < 2; ++n2)
                    acc[m2][n2] = __builtin_amdgcn_mfma_f32_16x16x32_f16(aF[m2], bF[n2], acc[m2][n2], 0, 0, 0);
        }
        __syncthreads();
    }

    // C/D layout: col = l&15, row = (l>>4)*4 + reg
#pragma unroll
    for (int m2 = 0; m2 < 2; ++m2) {
#pragma unroll
        for (int n2 = 0; n2 < 2; ++n2) {
            int n = wv * 32 + n2 * 16 + (l & 15);
#pragma unroll
            for (int r = 0; r < 4; ++r) {
                int m = m0 + m2 * 16 + (l >> 4) * 4 + r;
                z_part[((size_t)s * B_TOT + m) * NOUT + n] = acc[m2][n2][r];
            }
        }
    }
}

// ---------------------------------------------------------------------------
// Kernel 3: reduce 11 split-K partials, add bias, softplus on second half.
// ---------------------------------------------------------------------------
__global__ __launch_bounds__(256) void k_final(const float* __restrict__ z_part,
                                               const float* __restrict__ b_out,
                                               float* __restrict__ out)
{
    int idx = blockIdx.x * 256 + threadIdx.x;   // 2048*128
    int b = idx >> 7;
    int o = idx & 127;
    float z = b_out[o];
#pragma unroll
    for (int s = 0; s < KSPLIT; ++s) z += z_part[((size_t)s * B_TOT + b) * NOUT + o];
    if (o < 64) {
        out[(size_t)b * 64 + o] = z;
    } else {
        float sp = fmaxf(z, 0.f) + log1pf(expf(-fabsf(z)));
        out[131072 + (size_t)b * 64 + (o - 64)] = sp;
    }
}

// ---------------------------------------------------------------------------
extern "C" void kernel_launch(void* const* d_in, const int* in_sizes, int n_in,
                              void* d_out, int out_size, void* d_ws, size_t ws_size,
                              hipStream_t stream)
{
    const float* x     = (const float*)d_in[0];
    const float* w1    = (const float*)d_in[2];
    const float* b1    = (const float*)d_in[3];
    const float* w2    = (const float*)d_in[4];
    const float* b2    = (const float*)d_in[5];
    const float* w3    = (const float*)d_in[6];
    const float* b3    = (const float*)d_in[7];
    const float* w_out = (const float*)d_in[8];
    const float* b_out = (const float*)d_in[9];
    float* out = (float*)d_out;

    float* ws    = (float*)d_ws;
    f16*   sigh  = (f16*)ws;                        // 2048*8448 f16 = 8,650,752 f
    f16*   wh    = (f16*)(ws + 8650752);            // 128*8448 f16  =   540,672 f
    float* zpart = ws + 9191424;                    // 11*2048*128   = 2,883,584 f
    // total ~12.1M floats ~= 48.3 MB

    hipLaunchKernelGGL(k_augsig, dim3(544),  dim3(256), 0, stream,
                       x, w1, b1, w2, b2, w3, b3, w_out, wh, sigh);
    hipLaunchKernelGGL(k_gemm,   dim3(704),  dim3(256), 0, stream, sigh, wh, zpart);
    hipLaunchKernelGGL(k_final,  dim3(1024), dim3(256), 0, stream, zpart, b_out, out);
}

// Round 6
// 153.963 us; speedup vs baseline: 1.4693x; 1.0303x over previous
//
#include <hip/hip_runtime.h>
#include <math.h>

#define B_TOT 2048
#define D_INC 15
#define KW    40
#define CCH   20
#define LP    31
#define SIGCH 8420
#define SIGP  8448   // padded K; 8448 = 11*768, 768 = 12*64
#define NOUT  128
#define KSPLIT 11
#define KLEN  768    // per-split K: 12 chunks of BK=64

typedef _Float16 f16;
typedef _Float16 f16x8 __attribute__((ext_vector_type(8)));
typedef _Float16 f16x4 __attribute__((ext_vector_type(4)));
typedef float    f32x4 __attribute__((ext_vector_type(4)));
typedef float    f32x2 __attribute__((ext_vector_type(2)));

// ---------------------------------------------------------------------------
// Kernel 0: prep conv weights into MFMA A-fragment layout (fp16).
// wA[g][lane][j]  (g=0..19 k-chunks of 32): A[m=h][k], h=lane&15,
// kq=(lane>>4)*8+j, kk=2g+(kq>>4), c=kq&15 (c==15 -> 0 pad).
// ---------------------------------------------------------------------------
__global__ __launch_bounds__(256) void k_prep(const float* __restrict__ w1,
                                              f16* __restrict__ wA)
{
    const int ln = threadIdx.x & 63;
    const int wv = threadIdx.x >> 6;
    const int h  = ln & 15;
    const int q4 = ln >> 4;
    for (int gi = 0; gi < 5; ++gi) {
        int g = wv * 5 + gi;
        f16x8 v;
#pragma unroll
        for (int j = 0; j < 8; ++j) {
            int kq = q4 * 8 + j;
            int kk = 2 * g + (kq >> 4);
            int c  = kq & 15;
            v[j] = (c < D_INC) ? (f16)w1[h * 600 + c * 40 + kk] : (f16)0.f;
        }
        *(f16x8*)(wA + g * 512 + ln * 8) = v;
    }
}

// ---------------------------------------------------------------------------
// Kernel 1: fused augment (MFMA conv) + signature (+ w_out->fp16 convert on
// 32 side blocks). Blocks 0..511: 4 batches each, 1 wave per batch.
// LDS: xs 17.1K (aliased by incs) + xp16 9.2K (aliased by h1s) + pprev 10.5K
// + wsmall 1.4K = 38.2 KB.
// ---------------------------------------------------------------------------
__global__ __launch_bounds__(256, 2) void k_augsig(
    const float* __restrict__ x,  const f16* __restrict__ wA, const float* __restrict__ b1,
    const float* __restrict__ w2, const float* __restrict__ b2,
    const float* __restrict__ w3, const float* __restrict__ b3,
    const float* __restrict__ w_out, f16* __restrict__ wh, f16* __restrict__ sig)
{
    if (blockIdx.x >= 512) {
        // ---- convert w_out (128x8420 fp32) -> wh (128x8448 f16)
        int t0 = (blockIdx.x - 512) * 256 + threadIdx.x;     // 8192 threads
        for (int chunk = t0; chunk < 128 * 1056; chunk += 8192) {
            int o  = chunk / 1056;
            int cw = chunk - o * 1056;
            int c0 = cw * 8;
            f16x8 v;
            if (c0 + 8 <= SIGCH) {
                const float* src = w_out + (size_t)o * SIGCH + c0;
                float4 a = *(const float4*)src;
                float4 b = *(const float4*)(src + 4);
                v = (f16x8){(f16)a.x,(f16)a.y,(f16)a.z,(f16)a.w,
                            (f16)b.x,(f16)b.y,(f16)b.z,(f16)b.w};
            } else {
#pragma unroll
                for (int e = 0; e < 8; ++e) {
                    int c = c0 + e;
                    v[e] = (c < SIGCH) ? (f16)w_out[(size_t)o * SIGCH + c] : (f16)0.f;
                }
            }
            *(f16x8*)(wh + (size_t)o * SIGP + c0) = v;
        }
        return;
    }

    __shared__ float xs[4 * 1068];       // fp32 x; aliased by incs after MLP
    __shared__ f16   xp16[4 * 1152];     // pos-major fp16 x [pos][16]; alias h1s
    __shared__ float pprev[4 * 656];     // zero-prepended path
    __shared__ float wsmall[356];
    float* w2s = wsmall;        float* b2s = wsmall + 256;
    float* w3s = wsmall + 272;  float* b3s = wsmall + 336;
    float* b1s = wsmall + 340;
    float* h1s  = (float*)xp16;          // 2108 floats (alias, after conv)
    float* incs = xs;                    // 4*624 floats (alias, after MLP)

    const int tid = threadIdx.x;
    const int b0  = blockIdx.x * 4;

    for (int i = tid; i < 4 * 1050; i += 256) {
        int bl = i / 1050; int t = i - bl * 1050;
        xs[bl * 1068 + t] = x[(size_t)b0 * 1050 + i];
    }
    if (tid < 256) w2s[tid] = w2[tid];
    if (tid < 16)  b2s[tid] = b2[tid];
    if (tid < 64)  w3s[tid] = w3[tid];
    if (tid < 4)   b3s[tid] = b3[tid];
    if (tid < 16)  b1s[tid] = b1[tid];
    __syncthreads();

    // ---- build xp16: [bl][pos][c], c padded to 16 (c=15 -> 0)
    for (int r = tid; r < 280; r += 256) {
        int bl = r / 70; int pos = r - bl * 70;
        const float* src = xs + bl * 1068 + pos * 15;
        f16* dst = xp16 + bl * 1152 + pos * 16;
#pragma unroll
        for (int c = 0; c < 15; ++c) dst[c] = (f16)src[c];
        dst[15] = (f16)0.f;
    }
    __syncthreads();

    const int lane = tid & 63;
    const int w    = tid >> 6;
    const int n16  = lane & 15;
    const int q4   = lane >> 4;

    // ---- conv via MFMA: D[h][pos] per 16-pos tile, K = 40kk x 16c = 640
    f16x8 wa[20];
#pragma unroll
    for (int g = 0; g < 20; ++g) wa[g] = *(const f16x8*)(wA + g * 512 + lane * 8);

    f32x4 cacc[2];
#pragma unroll
    for (int tile = 0; tile < 2; ++tile) {
        const int pos0 = tile * 15;                 // tiles cover pos 0..15, 15..30
        f32x4 acc = {0.f, 0.f, 0.f, 0.f};
#pragma unroll
        for (int g = 0; g < 20; ++g) {
            const f16x8 bf = *(const f16x8*)&xp16[w * 1152 +
                (pos0 + n16 + 2 * g + (q4 >> 1)) * 16 + (q4 & 1) * 8];
            acc = __builtin_amdgcn_mfma_f32_16x16x32_f16(wa[g], bf, acc, 0, 0, 0);
        }
        cacc[tile] = acc;
    }
    __syncthreads();            // xp16 reads done before h1s alias write

    // C layout: col = lane&15 = pos-in-tile, row = q4*4+r = h
#pragma unroll
    for (int tile = 0; tile < 2; ++tile) {
        int pos = tile * 15 + n16;
#pragma unroll
        for (int r = 0; r < 4; ++r) {
            int h = q4 * 4 + r;
            h1s[(w * 31 + pos) * 17 + h] = fmaxf(cacc[tile][r] + b1s[h], 0.f);
        }
    }
    __syncthreads();

    // ---- small MLPs; write path rows into pprev (LDS)
    if (tid < 124) {
        const int bl2 = tid / 31;
        const int pos = tid - bl2 * 31;
        float hr[16];
#pragma unroll
        for (int c2 = 0; c2 < 16; ++c2) hr[c2] = h1s[tid * 17 + c2];
        float h2[16];
#pragma unroll
        for (int o = 0; o < 16; ++o) {
            float s = b2s[o];
#pragma unroll
            for (int c2 = 0; c2 < 16; ++c2) s += w2s[o * 16 + c2] * hr[c2];
            h2[o] = fmaxf(s, 0.f);
        }
        float h3[4];
#pragma unroll
        for (int f = 0; f < 4; ++f) {
            float s = b3s[f];
#pragma unroll
            for (int c2 = 0; c2 < 16; ++c2) s += w3s[f * 16 + c2] * h2[c2];
            h3[f] = s;
        }
        float* pr = pprev + bl2 * 656 + 20 + pos * 20;
#pragma unroll
        for (int d = 0; d < D_INC; ++d) pr[d] = xs[bl2 * 1068 + (pos + 39) * 15 + d];
        pr[15] = (float)pos * (1.0f / 30.0f);
#pragma unroll
        for (int f = 0; f < 4; ++f) pr[16 + f] = h3[f];
    } else {
        int z = tid - 124;                         // zero the prepend rows
        if (z < 80) pprev[(z / 20) * 656 + (z % 20)] = 0.f;
    }
    __syncthreads();           // pprev complete; xs now dead -> incs alias OK

    // ---- increments
    float* pp = pprev + w * 656;
    float* ic = incs  + w * 624;
    for (int i = lane; i < 620; i += 64) ic[i] = pp[20 + i] - pp[i];
    __syncthreads();

    // ---- signature t-loop (fp32; s3 via f32x2 packed FMA)
    int iv[7], jv[7];
#pragma unroll
    for (int q = 0; q < 7; ++q) {
        int p = lane + 64 * q;
        iv[q] = p / 20; jv[q] = p - iv[q] * 20;
    }
    float s2r[7];
    f32x2 s3v[7][10];
#pragma unroll
    for (int q = 0; q < 7; ++q) {
        s2r[q] = 0.f;
#pragma unroll
        for (int k = 0; k < 10; ++k) s3v[q][k] = (f32x2){0.f, 0.f};
    }

    for (int t = 0; t < LP; ++t) {
        const float* ip = &ic[t * 20];
        const float* sp = &pp[t * 20];              // s1 before step t
        f32x2 dv[10];
        const float4* dp = (const float4*)ip;
#pragma unroll
        for (int r = 0; r < 5; ++r) {
            float4 v = dp[r];
            dv[2*r]   = (f32x2){v.x, v.y};
            dv[2*r+1] = (f32x2){v.z, v.w};
        }
#pragma unroll
        for (int q = 0; q < 7; ++q) {
            if (lane + 64 * q < 400) {
                const float di  = ip[iv[q]];
                const float dj  = ip[jv[q]];
                const float s1i = sp[iv[q]];
                const float t2  = s2r[q] + (0.5f * s1i + (1.0f / 6.0f) * di) * dj;
                const f32x2 t2v = {t2, t2};
#pragma unroll
                for (int k = 0; k < 10; ++k) s3v[q][k] += t2v * dv[k];
                s2r[q] += (s1i + 0.5f * di) * dj;
            }
        }
    }

    const int b = b0 + w;
    f16* sg = sig + (size_t)b * SIGP;
    if (lane < 20) sg[lane] = (f16)pp[620 + lane];          // s1 = path[30]
#pragma unroll
    for (int q = 0; q < 6; ++q) sg[20 + q * 64 + lane] = (f16)s2r[q];
    if (lane < 16) sg[404 + lane] = (f16)s2r[6];
#pragma unroll
    for (int q = 0; q < 7; ++q) {
        int p = lane + 64 * q;
        if (p < 400) {
            f16* base = sg + 420 + p * 20;                  // 8-byte aligned
#pragma unroll
            for (int g = 0; g < 5; ++g) {
                f16x4 v = { (f16)s3v[q][2*g][0],   (f16)s3v[q][2*g][1],
                            (f16)s3v[q][2*g+1][0], (f16)s3v[q][2*g+1][1] };
                *(f16x4*)(base + 4 * g) = v;
            }
        }
    }
    if (lane < 28) sg[SIGCH + lane] = (f16)0.f;             // zero K pad
}

// ---------------------------------------------------------------------------
// Kernel 2: fp16 MFMA GEMM, BM32/BN128/BK64, split-K 11 (12 iters of 64).
// grid = 64 mtiles x 11 splits = 704 blocks. 8 MFMA per barrier.
// ---------------------------------------------------------------------------
__global__ __launch_bounds__(256) void k_gemm(const f16* __restrict__ sigh,
                                              const f16* __restrict__ wh,
                                              float* __restrict__ z_part)
{
    __shared__ f16 As[2048];    // 4 KB : 8 g-groups x 32 m x 8
    __shared__ f16 Bs[8192];    // 16 KB: 8 g-groups x 128 n x 8
    const int tid = threadIdx.x;
    const int l   = tid & 63;
    const int wv  = tid >> 6;
    const int mt  = blockIdx.x / KSPLIT;
    const int s   = blockIdx.x - mt * KSPLIT;
    const int m0  = mt * 32;
    const int kb  = s * KLEN;

    const f32x4 z4 = {0.f, 0.f, 0.f, 0.f};
    f32x4 acc[2][2];
    acc[0][0] = z4; acc[0][1] = z4; acc[1][0] = z4; acc[1][1] = z4;

    const size_t gA = (size_t)(m0 + (tid & 31)) * SIGP + kb + (tid >> 5) * 8;
    size_t gB[4];
#pragma unroll
    for (int r = 0; r < 4; ++r) {
        int slot = r * 256 + tid;
        gB[r] = (size_t)(slot & 127) * SIGP + kb + (slot >> 7) * 8;
    }

    f16x8 aR = *(const f16x8*)(sigh + gA);
    f16x8 bR[4];
#pragma unroll
    for (int r = 0; r < 4; ++r) bR[r] = *(const f16x8*)(wh + gB[r]);

    const int kg   = l >> 4;
    const int mrow = l & 15;

    for (int ch = 0; ch < 12; ++ch) {
        *(f16x8*)&As[tid * 8] = aR;
#pragma unroll
        for (int r = 0; r < 4; ++r) *(f16x8*)&Bs[(r * 256 + tid) * 8] = bR[r];
        __syncthreads();

        if (ch < 11) {                     // prefetch next BK=64 chunk
            int koff = (ch + 1) * 64;
            aR = *(const f16x8*)(sigh + gA + koff);
#pragma unroll
            for (int r = 0; r < 4; ++r) bR[r] = *(const f16x8*)(wh + gB[r] + koff);
        }

#pragma unroll
        for (int kc = 0; kc < 2; ++kc) {
            f16x8 aF[2], bF[2];
#pragma unroll
            for (int m2 = 0; m2 < 2; ++m2)
                aF[m2] = *(const f16x8*)&As[((kc * 4 + kg) * 32 + m2 * 16 + mrow) * 8];
#pragma unroll
            for (int n2 = 0; n2 < 2; ++n2)
                bF[n2] = *(const f16x8*)&Bs[((kc * 4 + kg) * 128 + wv * 32 + n2 * 16 + mrow) * 8];
#pragma unroll
            for (int m2 = 0; m2 < 2; ++m2)
#pragma unroll
                for (int n2 = 0; n2 < 2; ++n2)
                    acc[m2][n2] = __builtin_amdgcn_mfma_f32_16x16x32_f16(aF[m2], bF[n2], acc[m2][n2], 0, 0, 0);
        }
        __syncthreads();
    }

#pragma unroll
    for (int m2 = 0; m2 < 2; ++m2) {
#pragma unroll
        for (int n2 = 0; n2 < 2; ++n2) {
            int n = wv * 32 + n2 * 16 + (l & 15);
#pragma unroll
            for (int r = 0; r < 4; ++r) {
                int m = m0 + m2 * 16 + (l >> 4) * 4 + r;
                z_part[((size_t)s * B_TOT + m) * NOUT + n] = acc[m2][n2][r];
            }
        }
    }
}

// ---------------------------------------------------------------------------
// Kernel 3: reduce 11 split-K partials, add bias, softplus on second half.
// ---------------------------------------------------------------------------
__global__ __launch_bounds__(256) void k_final(const float* __restrict__ z_part,
                                               const float* __restrict__ b_out,
                                               float* __restrict__ out)
{
    int idx = blockIdx.x * 256 + threadIdx.x;   // 2048*128
    int b = idx >> 7;
    int o = idx & 127;
    float z = b_out[o];
#pragma unroll
    for (int s = 0; s < KSPLIT; ++s) z += z_part[((size_t)s * B_TOT + b) * NOUT + o];
    if (o < 64) {
        out[(size_t)b * 64 + o] = z;
    } else {
        float sp = fmaxf(z, 0.f) + log1pf(expf(-fabsf(z)));
        out[131072 + (size_t)b * 64 + (o - 64)] = sp;
    }
}

// ---------------------------------------------------------------------------
extern "C" void kernel_launch(void* const* d_in, const int* in_sizes, int n_in,
                              void* d_out, int out_size, void* d_ws, size_t ws_size,
                              hipStream_t stream)
{
    const float* x     = (const float*)d_in[0];
    const float* w1    = (const float*)d_in[2];
    const float* b1    = (const float*)d_in[3];
    const float* w2    = (const float*)d_in[4];
    const float* b2    = (const float*)d_in[5];
    const float* w3    = (const float*)d_in[6];
    const float* b3    = (const float*)d_in[7];
    const float* w_out = (const float*)d_in[8];
    const float* b_out = (const float*)d_in[9];
    float* out = (float*)d_out;

    // NOTE float-unit offsets: N f16 elements occupy N/2 float units.
    float* ws    = (float*)d_ws;
    f16*   sigh  = (f16*)ws;                        // 2048*8448 f16 = 8,650,752 float-units
    f16*   wh    = (f16*)(ws + 8650752);            // 128*8448 f16  =   540,672 float-units
    f16*   wA    = (f16*)(ws + 9191424);            // 10,240 f16    =     5,120 float-units
    float* zpart = ws + 9196544;                    // 11*2048*128   = 2,883,584 floats
    // total 12,080,128 floats ~= 48.3 MB

    hipLaunchKernelGGL(k_prep,   dim3(1),    dim3(256), 0, stream, w1, wA);
    hipLaunchKernelGGL(k_augsig, dim3(544),  dim3(256), 0, stream,
                       x, wA, b1, w2, b2, w3, b3, w_out, wh, sigh);
    hipLaunchKernelGGL(k_gemm,   dim3(704),  dim3(256), 0, stream, sigh, wh, zpart);
    hipLaunchKernelGGL(k_final,  dim3(1024), dim3(256), 0, stream, zpart, b_out, out);
}

// Round 7
// 143.752 us; speedup vs baseline: 1.5737x; 1.0710x over previous
//
#include <hip/hip_runtime.h>
#include <math.h>

#define B_TOT 2048
#define D_INC 15
#define KW    40
#define CCH   20
#define LP    31
#define SIGCH 8420
#define SIGP  8448   // padded K; 8448 = 11*768, 768 = 12*64
#define NOUT  128
#define KSPLIT 11
#define KLEN  768    // per-split K: 12 chunks of BK=64

typedef _Float16 f16;
typedef _Float16 f16x8 __attribute__((ext_vector_type(8)));
typedef _Float16 f16x4 __attribute__((ext_vector_type(4)));
typedef _Float16 f16x2 __attribute__((ext_vector_type(2)));
typedef float    f32x4 __attribute__((ext_vector_type(4)));

// ---------------------------------------------------------------------------
// Kernel 0: prep conv weights into MFMA A-fragment layout (fp16).
// ---------------------------------------------------------------------------
__global__ __launch_bounds__(256) void k_prep(const float* __restrict__ w1,
                                              f16* __restrict__ wA)
{
    const int ln = threadIdx.x & 63;
    const int wv = threadIdx.x >> 6;
    const int h  = ln & 15;
    const int q4 = ln >> 4;
    for (int gi = 0; gi < 5; ++gi) {
        int g = wv * 5 + gi;
        f16x8 v;
#pragma unroll
        for (int j = 0; j < 8; ++j) {
            int kq = q4 * 8 + j;
            int kk = 2 * g + (kq >> 4);
            int c  = kq & 15;
            v[j] = (c < D_INC) ? (f16)w1[h * 600 + c * 40 + kk] : (f16)0.f;
        }
        *(f16x8*)(wA + g * 512 + ln * 8) = v;
    }
}

// ---------------------------------------------------------------------------
// Kernel 1: fused augment (MFMA conv) + signature-as-mini-GEMM (MFMA).
// Blocks 0..511: 4 batches, 1 wave/batch. Blocks 512..543: w_out->f16 convert.
// Signature algebra: S3[p][k] = sum_t U[t][p]*SufD[t][k] + E2[t][p]*d[t][k],
//   U[t][p=(i,j)] = (s1pre+0.5d)_i * d_j,  E2 = (0.5*s1pre + d/6)_i * d_j,
//   SufD[t][k] = sum_{t'>t} d[t'][k];  s2[p] = sum_t U[t][p] (ones col in V).
// W-frags built in registers from transposed atr/etr/dtr (stride 36, b128).
// ---------------------------------------------------------------------------
__global__ __launch_bounds__(256, 2) void k_augsig(
    const float* __restrict__ x,  const f16* __restrict__ wA, const float* __restrict__ b1,
    const float* __restrict__ w2, const float* __restrict__ b2,
    const float* __restrict__ w3, const float* __restrict__ b3,
    const float* __restrict__ w_out, f16* __restrict__ wh, f16* __restrict__ sig)
{
    if (blockIdx.x >= 512) {
        int t0 = (blockIdx.x - 512) * 256 + threadIdx.x;     // 8192 threads
        for (int chunk = t0; chunk < 128 * 1056; chunk += 8192) {
            int o  = chunk / 1056;
            int cw = chunk - o * 1056;
            int c0 = cw * 8;
            f16x8 v;
            if (c0 + 8 <= SIGCH) {
                const float* src = w_out + (size_t)o * SIGCH + c0;
                float4 a = *(const float4*)src;
                float4 b = *(const float4*)(src + 4);
                v = (f16x8){(f16)a.x,(f16)a.y,(f16)a.z,(f16)a.w,
                            (f16)b.x,(f16)b.y,(f16)b.z,(f16)b.w};
            } else {
#pragma unroll
                for (int e = 0; e < 8; ++e) {
                    int c = c0 + e;
                    v[e] = (c < SIGCH) ? (f16)w_out[(size_t)o * SIGCH + c] : (f16)0.f;
                }
            }
            *(f16x8*)(wh + (size_t)o * SIGP + c0) = v;
        }
        return;
    }

    // LDS pool (~63.4 KB -> 2 blocks/CU):
    //  [0..13248)   per-batch sig scratch (4 x 3312: dtr 720 | atr 720 | etr 720 | V 1152)
    //               early-phase aliases: xs @0 (4272 f), xp16/h1s @4272 (2304 f)
    //  [13248..15872) pprev (4 x 656)
    //  [15872..16228) wsmall
    __shared__ float pool[16228];
    float* xs    = pool;                         // fp32 x (dead after MLP)
    f16*   xp16  = (f16*)(pool + 4272);          // pos-major f16 x (dead after conv)
    float* h1s   = (float*)xp16;                 // alias after conv
    float* pprev = pool + 13248;
    float* wsmall= pool + 15872;
    float* w2s = wsmall;        float* b2s = wsmall + 256;
    float* w3s = wsmall + 272;  float* b3s = wsmall + 336;
    float* b1s = wsmall + 340;

    const int tid = threadIdx.x;
    const int b0  = blockIdx.x * 4;

    for (int i = tid; i < 4 * 1050; i += 256) {
        int bl = i / 1050; int t = i - bl * 1050;
        xs[bl * 1068 + t] = x[(size_t)b0 * 1050 + i];
    }
    if (tid < 256) w2s[tid] = w2[tid];
    if (tid < 16)  b2s[tid] = b2[tid];
    if (tid < 64)  w3s[tid] = w3[tid];
    if (tid < 4)   b3s[tid] = b3[tid];
    if (tid < 16)  b1s[tid] = b1[tid];
    __syncthreads();

    // ---- build xp16: [bl][pos][c], c padded to 16 (c=15 -> 0)
    for (int r = tid; r < 280; r += 256) {
        int bl = r / 70; int pos = r - bl * 70;
        const float* src = xs + bl * 1068 + pos * 15;
        f16* dst = xp16 + bl * 1152 + pos * 16;
#pragma unroll
        for (int c = 0; c < 15; ++c) dst[c] = (f16)src[c];
        dst[15] = (f16)0.f;
    }
    __syncthreads();

    const int lane = tid & 63;
    const int w    = tid >> 6;
    const int n16  = lane & 15;
    const int q4   = lane >> 4;

    // ---- conv via MFMA
    f16x8 wa[20];
#pragma unroll
    for (int g = 0; g < 20; ++g) wa[g] = *(const f16x8*)(wA + g * 512 + lane * 8);

    f32x4 cacc[2];
#pragma unroll
    for (int tile = 0; tile < 2; ++tile) {
        const int pos0 = tile * 15;
        f32x4 acc = {0.f, 0.f, 0.f, 0.f};
#pragma unroll
        for (int g = 0; g < 20; ++g) {
            const f16x8 bf = *(const f16x8*)&xp16[w * 1152 +
                (pos0 + n16 + 2 * g + (q4 >> 1)) * 16 + (q4 & 1) * 8];
            acc = __builtin_amdgcn_mfma_f32_16x16x32_f16(wa[g], bf, acc, 0, 0, 0);
        }
        cacc[tile] = acc;
    }
    __syncthreads();            // xp16 reads done before h1s alias write

#pragma unroll
    for (int tile = 0; tile < 2; ++tile) {
        int pos = tile * 15 + n16;
#pragma unroll
        for (int r = 0; r < 4; ++r) {
            int h = q4 * 4 + r;
            h1s[(w * 31 + pos) * 17 + h] = fmaxf(cacc[tile][r] + b1s[h], 0.f);
        }
    }
    __syncthreads();

    // ---- small MLPs; write path rows into pprev (LDS)
    if (tid < 124) {
        const int bl2 = tid / 31;
        const int pos = tid - bl2 * 31;
        float hr[16];
#pragma unroll
        for (int c2 = 0; c2 < 16; ++c2) hr[c2] = h1s[tid * 17 + c2];
        float h2[16];
#pragma unroll
        for (int o = 0; o < 16; ++o) {
            float s = b2s[o];
#pragma unroll
            for (int c2 = 0; c2 < 16; ++c2) s += w2s[o * 16 + c2] * hr[c2];
            h2[o] = fmaxf(s, 0.f);
        }
        float h3[4];
#pragma unroll
        for (int f = 0; f < 4; ++f) {
            float s = b3s[f];
#pragma unroll
            for (int c2 = 0; c2 < 16; ++c2) s += w3s[f * 16 + c2] * h2[c2];
            h3[f] = s;
        }
        float* pr = pprev + bl2 * 656 + 20 + pos * 20;
#pragma unroll
        for (int d = 0; d < D_INC; ++d) pr[d] = xs[bl2 * 1068 + (pos + 39) * 15 + d];
        pr[15] = (float)pos * (1.0f / 30.0f);
#pragma unroll
        for (int f = 0; f < 4; ++f) pr[16 + f] = h3[f];
    } else {
        int z = tid - 124;
        if (z < 80) pprev[(z / 20) * 656 + (z % 20)] = 0.f;
    }
    __syncthreads();           // pprev complete; xs/xp16 dead -> scratch alias OK

    // ---- per-batch scratch
    float* pp  = pprev + w * 656;
    float* dtr = pool + w * 3312;        // [c][t], stride 36, t=31 pad 0
    float* atr = dtr + 720;
    float* etr = dtr + 1440;
    f16*   Vb  = (f16*)(dtr + 2160);     // [n<32][k<64], row stride 72 f16

    // (a) transposed d / A / E
    for (int e = lane; e < 620; e += 64) {
        int c = e / 31, t = e - c * 31;
        float p0 = pp[t * 20 + c];
        float d  = pp[(t + 1) * 20 + c] - p0;
        dtr[c * 36 + t] = d;
        atr[c * 36 + t] = p0 + 0.5f * d;
        etr[c * 36 + t] = 0.5f * p0 + d * (1.0f / 6.0f);
    }
    if (lane < 20) {
        dtr[lane * 36 + 31] = 0.f;
        atr[lane * 36 + 31] = 0.f;
        etr[lane * 36 + 31] = 0.f;
    }
    __syncthreads();

    // (b) V = [SufD | d] rows 0..19; row 20 = ones/zeros (s2); rows 21..31 = 0
    if (lane < 20) {
        const int n = lane;
        f16* vr = Vb + n * 72;
        float s = 0.f;
        for (int t = 30; t >= 0; --t) {
            float dv = dtr[n * 36 + t];
            vr[t]      = (f16)s;          // SufD[t] = sum_{t'>t} d
            vr[32 + t] = (f16)dv;
            s += dv;
        }
        vr[31] = (f16)0.f;
        vr[63] = (f16)0.f;
    } else if (lane == 20) {
        f16* vr = Vb + 20 * 72;
        for (int k = 0; k < 64; ++k) vr[k] = (k < 31) ? (f16)1.f : (f16)0.f;
    }
    for (int e = lane; e < 11 * 32; e += 64) {       // zero rows 21..31
        int row = 21 + (e >> 5);
        int kk  = (e & 31) * 2;
        *(f16x2*)(Vb + row * 72 + kk) = (f16x2){(f16)0.f, (f16)0.f};
    }
    __syncthreads();

    // hoisted B-fragments: V[n = nt*16 + l16][kc*32 + quad*8 + j]
    f16x8 bf[2][2];
#pragma unroll
    for (int kc = 0; kc < 2; ++kc)
#pragma unroll
        for (int nt = 0; nt < 2; ++nt)
            bf[kc][nt] = *(const f16x8*)(Vb + (nt * 16 + n16) * 72 + kc * 32 + q4 * 8);

    const int b = b0 + w;
    f16* sg = sig + (size_t)b * SIGP;

    // m-loop: 25 tiles of 16 pairs; W-frags built in registers
    for (int mt = 0; mt < 25; ++mt) {
        const int p = mt * 16 + n16;
        const int i = p / 20, j = p - i * 20;
        const float4* ap = (const float4*)(atr + i * 36 + q4 * 8);
        const float4* ep = (const float4*)(etr + i * 36 + q4 * 8);
        const float4* dp = (const float4*)(dtr + j * 36 + q4 * 8);
        float4 a0 = ap[0], a1 = ap[1];
        float4 e0 = ep[0], e1 = ep[1];
        float4 d0 = dp[0], d1 = dp[1];
        f16x8 uf, ef;
        uf[0]=(f16)(a0.x*d0.x); uf[1]=(f16)(a0.y*d0.y); uf[2]=(f16)(a0.z*d0.z); uf[3]=(f16)(a0.w*d0.w);
        uf[4]=(f16)(a1.x*d1.x); uf[5]=(f16)(a1.y*d1.y); uf[6]=(f16)(a1.z*d1.z); uf[7]=(f16)(a1.w*d1.w);
        ef[0]=(f16)(e0.x*d0.x); ef[1]=(f16)(e0.y*d0.y); ef[2]=(f16)(e0.z*d0.z); ef[3]=(f16)(e0.w*d0.w);
        ef[4]=(f16)(e1.x*d1.x); ef[5]=(f16)(e1.y*d1.y); ef[6]=(f16)(e1.z*d1.z); ef[7]=(f16)(e1.w*d1.w);

        f32x4 acc0 = {0.f,0.f,0.f,0.f}, acc1 = {0.f,0.f,0.f,0.f};
        acc0 = __builtin_amdgcn_mfma_f32_16x16x32_f16(uf, bf[0][0], acc0, 0, 0, 0);
        acc0 = __builtin_amdgcn_mfma_f32_16x16x32_f16(ef, bf[1][0], acc0, 0, 0, 0);
        acc1 = __builtin_amdgcn_mfma_f32_16x16x32_f16(uf, bf[0][1], acc1, 0, 0, 0);
        acc1 = __builtin_amdgcn_mfma_f32_16x16x32_f16(ef, bf[1][1], acc1, 0, 0, 0);

        // C/D: col = n16 (n within tile), row = q4*4 + r (p within tile)
        const int prow0 = mt * 16 + q4 * 4;
#pragma unroll
        for (int r = 0; r < 4; ++r) {
            const int p2 = prow0 + r;
            sg[420 + p2 * 20 + n16] = (f16)acc0[r];                 // s3 cols 0..15
            if (n16 < 4)       sg[420 + p2 * 20 + 16 + n16] = (f16)acc1[r];  // 16..19
            else if (n16 == 4) sg[20 + p2] = (f16)acc1[r];          // s2 (ones col)
        }
    }

    if (lane < 20) sg[lane] = (f16)pp[620 + lane];          // s1 = path[30]
    if (lane < 28) sg[SIGCH + lane] = (f16)0.f;             // zero K pad
}

// ---------------------------------------------------------------------------
// Kernel 2: fp16 MFMA GEMM, BM32/BN128/BK64, split-K 11 (12 iters of 64).
// ---------------------------------------------------------------------------
__global__ __launch_bounds__(256) void k_gemm(const f16* __restrict__ sigh,
                                              const f16* __restrict__ wh,
                                              float* __restrict__ z_part)
{
    __shared__ f16 As[2048];
    __shared__ f16 Bs[8192];
    const int tid = threadIdx.x;
    const int l   = tid & 63;
    const int wv  = tid >> 6;
    const int mt  = blockIdx.x / KSPLIT;
    const int s   = blockIdx.x - mt * KSPLIT;
    const int m0  = mt * 32;
    const int kb  = s * KLEN;

    const f32x4 z4 = {0.f, 0.f, 0.f, 0.f};
    f32x4 acc[2][2];
    acc[0][0] = z4; acc[0][1] = z4; acc[1][0] = z4; acc[1][1] = z4;

    const size_t gA = (size_t)(m0 + (tid & 31)) * SIGP + kb + (tid >> 5) * 8;
    size_t gB[4];
#pragma unroll
    for (int r = 0; r < 4; ++r) {
        int slot = r * 256 + tid;
        gB[r] = (size_t)(slot & 127) * SIGP + kb + (slot >> 7) * 8;
    }

    f16x8 aR = *(const f16x8*)(sigh + gA);
    f16x8 bR[4];
#pragma unroll
    for (int r = 0; r < 4; ++r) bR[r] = *(const f16x8*)(wh + gB[r]);

    const int kg   = l >> 4;
    const int mrow = l & 15;

    for (int ch = 0; ch < 12; ++ch) {
        *(f16x8*)&As[tid * 8] = aR;
#pragma unroll
        for (int r = 0; r < 4; ++r) *(f16x8*)&Bs[(r * 256 + tid) * 8] = bR[r];
        __syncthreads();

        if (ch < 11) {
            int koff = (ch + 1) * 64;
            aR = *(const f16x8*)(sigh + gA + koff);
#pragma unroll
            for (int r = 0; r < 4; ++r) bR[r] = *(const f16x8*)(wh + gB[r] + koff);
        }

#pragma unroll
        for (int kc = 0; kc < 2; ++kc) {
            f16x8 aF[2], bF[2];
#pragma unroll
            for (int m2 = 0; m2 < 2; ++m2)
                aF[m2] = *(const f16x8*)&As[((kc * 4 + kg) * 32 + m2 * 16 + mrow) * 8];
#pragma unroll
            for (int n2 = 0; n2 < 2; ++n2)
                bF[n2] = *(const f16x8*)&Bs[((kc * 4 + kg) * 128 + wv * 32 + n2 * 16 + mrow) * 8];
#pragma unroll
            for (int m2 = 0; m2 < 2; ++m2)
#pragma unroll
                for (int n2 = 0; n2 < 2; ++n2)
                    acc[m2][n2] = __builtin_amdgcn_mfma_f32_16x16x32_f16(aF[m2], bF[n2], acc[m2][n2], 0, 0, 0);
        }
        __syncthreads();
    }

#pragma unroll
    for (int m2 = 0; m2 < 2; ++m2) {
#pragma unroll
        for (int n2 = 0; n2 < 2; ++n2) {
            int n = wv * 32 + n2 * 16 + (l & 15);
#pragma unroll
            for (int r = 0; r < 4; ++r) {
                int m = m0 + m2 * 16 + (l >> 4) * 4 + r;
                z_part[((size_t)s * B_TOT + m) * NOUT + n] = acc[m2][n2][r];
            }
        }
    }
}

// ---------------------------------------------------------------------------
// Kernel 3: reduce 11 split-K partials, add bias, softplus on second half.
// ---------------------------------------------------------------------------
__global__ __launch_bounds__(256) void k_final(const float* __restrict__ z_part,
                                               const float* __restrict__ b_out,
                                               float* __restrict__ out)
{
    int idx = blockIdx.x * 256 + threadIdx.x;   // 2048*128
    int b = idx >> 7;
    int o = idx & 127;
    float z = b_out[o];
#pragma unroll
    for (int s = 0; s < KSPLIT; ++s) z += z_part[((size_t)s * B_TOT + b) * NOUT + o];
    if (o < 64) {
        out[(size_t)b * 64 + o] = z;
    } else {
        float sp = fmaxf(z, 0.f) + log1pf(expf(-fabsf(z)));
        out[131072 + (size_t)b * 64 + (o - 64)] = sp;
    }
}

// ---------------------------------------------------------------------------
extern "C" void kernel_launch(void* const* d_in, const int* in_sizes, int n_in,
                              void* d_out, int out_size, void* d_ws, size_t ws_size,
                              hipStream_t stream)
{
    const float* x     = (const float*)d_in[0];
    const float* w1    = (const float*)d_in[2];
    const float* b1    = (const float*)d_in[3];
    const float* w2    = (const float*)d_in[4];
    const float* b2    = (const float*)d_in[5];
    const float* w3    = (const float*)d_in[6];
    const float* b3    = (const float*)d_in[7];
    const float* w_out = (const float*)d_in[8];
    const float* b_out = (const float*)d_in[9];
    float* out = (float*)d_out;

    // float-unit offsets: N f16 elements occupy N/2 float units.
    float* ws    = (float*)d_ws;
    f16*   sigh  = (f16*)ws;                        // 2048*8448 f16 = 8,650,752 fu
    f16*   wh    = (f16*)(ws + 8650752);            // 128*8448 f16  =   540,672 fu
    f16*   wA    = (f16*)(ws + 9191424);            // 10,240 f16    =     5,120 fu
    float* zpart = ws + 9196544;                    // 11*2048*128   = 2,883,584 f
    // total 12,080,128 floats ~= 48.3 MB

    hipLaunchKernelGGL(k_prep,   dim3(1),    dim3(256), 0, stream, w1, wA);
    hipLaunchKernelGGL(k_augsig, dim3(544),  dim3(256), 0, stream,
                       x, wA, b1, w2, b2, w3, b3, w_out, wh, sigh);
    hipLaunchKernelGGL(k_gemm,   dim3(704),  dim3(256), 0, stream, sigh, wh, zpart);
    hipLaunchKernelGGL(k_final,  dim3(1024), dim3(256), 0, stream, zpart, b_out, out);
}